// Round 1
// baseline (1990.080 us; speedup 1.0000x reference)
//
#include <hip/hip_runtime.h>
#include <hip/hip_bf16.h>
#include <stdint.h>

// Problem constants
#define N_ROWS 8192
#define M0C 2672    // C0 + P0 + P1 = 64 + 2080 + 528
#define M1C 2080    // C1 + C0*C1
#define A1C 496
#define P1C 528
#define KP  2688    // M0 padded to multiple of 128 (and 32 for K)
#define NP2 5888    // NUM_IRREPS (5776) padded to multiple of 128
#define NIR 5776

typedef __attribute__((ext_vector_type(8))) _Float16 half8;
typedef __attribute__((ext_vector_type(4))) float floatx4;

__device__ __forceinline__ void async_copy16(const _Float16* g, _Float16* l) {
  __builtin_amdgcn_global_load_lds(
      (__attribute__((address_space(1))) void*)(g),
      (__attribute__((address_space(3))) void*)(l), 16, 0, 0);
}

// ---------------------------------------------------------------------------
// Transpose + fp32->fp16 convert with zero padding.
// dst[r][c] = (c < srcR && r < srcC) ? src[c][r] : 0;  dst is [dstR][dstC(ld)]
// grid: x = dstC/32, y = dstR/32
// ---------------------------------------------------------------------------
__global__ __launch_bounds__(256) void transpose_cvt_kernel(
    const float* __restrict__ src, _Float16* __restrict__ dst,
    int srcR, int srcC, int dstC) {
  __shared__ float tile[32][33];
  const int t = threadIdx.x, tx = t & 31, ty = t >> 5;
  const int bx = blockIdx.x, by = blockIdx.y;
#pragma unroll
  for (int i = 0; i < 4; ++i) {
    int sr = bx * 32 + ty + i * 8;   // src row (k dim)
    int sc = by * 32 + tx;           // src col
    tile[ty + i * 8][tx] = (sr < srcR && sc < srcC) ? src[(size_t)sr * srcC + sc] : 0.f;
  }
  __syncthreads();
#pragma unroll
  for (int i = 0; i < 4; ++i) {
    int dr = by * 32 + ty + i * 8;
    int dc = bx * 32 + tx;
    dst[(size_t)dr * dstC + dc] = (_Float16)tile[tx][ty + i * 8];
  }
}

// ---------------------------------------------------------------------------
// triu_indices(C) pair decode: p -> (a, b), b >= a. offs(a) = a*C - a(a-1)/2
// ---------------------------------------------------------------------------
__device__ __forceinline__ void triu_ab(int p, int C, int& a, int& b) {
  float fC = (float)C + 0.5f;
  int ai = (int)(fC - sqrtf(fC * fC - 2.0f * (float)p));
  if (ai < 0) ai = 0;
  while (ai > 0 && ai * C - ai * (ai - 1) / 2 > p) --ai;
  while ((ai + 1) * C - (ai + 1) * ai / 2 <= p) ++ai;
  a = ai;
  b = p - (ai * C - ai * (ai - 1) / 2) + ai;
}

// ---------------------------------------------------------------------------
// f0 = [x_s (64) | ss (2080) | vv0 (528) | zero pad (16)]  as fp16 [N][KP]
// ---------------------------------------------------------------------------
__global__ __launch_bounds__(256) void build_f0_kernel(
    const float* __restrict__ xs_g, const float* __restrict__ xv_g,
    _Float16* __restrict__ f0p) {
  __shared__ float xs[64];
  __shared__ float xv[96];
  const int t = threadIdx.x;
  const size_t n = blockIdx.x;
  if (t < 64) xs[t] = xs_g[n * 64 + t];
  else if (t < 160) xv[t - 64] = xv_g[n * 96 + (t - 64)];
  __syncthreads();
  for (int c = t; c < KP; c += 256) {
    float v;
    if (c < 64) {
      v = xs[c];
    } else if (c < 2144) {                       // ss: pair products of x_s
      int a, b;
      triu_ab(c - 64, 64, a, b);
      v = xs[a] * xs[b] * ((a == b) ? 0.70710678118654752f : 1.f);
    } else if (c < M0C) {                        // vv0: pair dots of x_v
      int a, b;
      triu_ab(c - 2144, 32, a, b);
      float d = xv[a * 3] * xv[b * 3] + xv[a * 3 + 1] * xv[b * 3 + 1] +
                xv[a * 3 + 2] * xv[b * 3 + 2];
      v = d * ((a == b) ? 0.70710678118654752f : 1.f) * 0.57735026918962576f;
    } else {
      v = 0.f;                                   // pad
    }
    f0p[n * KP + c] = (_Float16)v;
  }
}

// ---------------------------------------------------------------------------
// fp16 MFMA GEMM, m97 structure: C = op(A @ B^T_storage)
//   A: [rows][K] fp16 row-major, B: [cols][K] fp16 row-major (i.e. B^T of the
//   math B), C: [rows][ldc] fp16. 128x128 block tile, 4 waves of 64x64,
//   BK=32, single LDS buffer, global_load_lds width 16, 2-barrier K-loop.
// ---------------------------------------------------------------------------
template <bool SILU>
__global__ __launch_bounds__(256, 3) void gemm_kernel(
    const _Float16* __restrict__ A, const _Float16* __restrict__ B,
    _Float16* __restrict__ C, int K, int lda, int ldb, int ldc) {
  __shared__ alignas(16) _Float16 As[128 * 32];
  __shared__ alignas(16) _Float16 Bs[128 * 32];
  const int tid = threadIdx.x;
  const size_t row0 = (size_t)blockIdx.y * 128;
  const size_t col0 = (size_t)blockIdx.x * 128;

  // staging: chunk c = tid + i*256 -> tile row c>>2, k-chunk (c&3)*8
  const _Float16* ga[2];
  const _Float16* gb[2];
  _Float16* la[2];
  _Float16* lb[2];
#pragma unroll
  for (int i = 0; i < 2; ++i) {
    int c = tid + i * 256;
    int r = c >> 2, kc = (c & 3) * 8;
    ga[i] = A + (row0 + r) * lda + kc;
    gb[i] = B + (col0 + r) * ldb + kc;
    la[i] = &As[c * 8];
    lb[i] = &Bs[c * 8];
  }

  const int lane = tid & 63;
  const int wave = tid >> 6;
  const int wm = (wave & 1) * 64;
  const int wn = (wave >> 1) * 64;
  const int m16 = lane & 15;
  const int quad = lane >> 4;
  int aoff[4], boff[4];
#pragma unroll
  for (int i = 0; i < 4; ++i) {
    aoff[i] = (wm + i * 16 + m16) * 32 + quad * 8;
    boff[i] = (wn + i * 16 + m16) * 32 + quad * 8;
  }

  floatx4 acc[4][4] = {};

  for (int k = 0; k < K; k += 32) {
    if (k) __syncthreads();  // previous tile's ds_reads done before overwrite
#pragma unroll
    for (int i = 0; i < 2; ++i) {
      async_copy16(ga[i] + k, la[i]);
      async_copy16(gb[i] + k, lb[i]);
    }
    __syncthreads();  // compiler emits vmcnt(0) drain before s_barrier

    half8 af[4], bf[4];
#pragma unroll
    for (int i = 0; i < 4; ++i) af[i] = *(const half8*)&As[aoff[i]];
#pragma unroll
    for (int j = 0; j < 4; ++j) bf[j] = *(const half8*)&Bs[boff[j]];
#pragma unroll
    for (int i = 0; i < 4; ++i)
#pragma unroll
      for (int j = 0; j < 4; ++j)
        acc[i][j] = __builtin_amdgcn_mfma_f32_16x16x32_f16(af[i], bf[j], acc[i][j], 0, 0, 0);
  }

  // C/D layout (verified m89/m91): col = lane&15, row = quad*4 + reg
#pragma unroll
  for (int i = 0; i < 4; ++i) {
    size_t r = row0 + wm + i * 16 + quad * 4;
#pragma unroll
    for (int j = 0; j < 4; ++j) {
      size_t cc = col0 + wn + j * 16 + m16;
#pragma unroll
      for (int rr = 0; rr < 4; ++rr) {
        float v = acc[i][j][rr];
        if (SILU) v = v / (1.f + __expf(-v));
        C[(r + rr) * ldc + cc] = (_Float16)v;
      }
    }
  }
}

// ---------------------------------------------------------------------------
// Epilogue: 8 rows per block. Gated o0/o1/o1e/o2 dot products in fp32.
// G layout: [0,2672)=g0  [2672,4752)=g1  [4752,5248)=g1e  [5248,5776)=g2
// out row layout: [0,64)=o0  [64,160)=o1 (o*3+i)  [160,208)=o1e  [208,288)=o2 (o*5+m)
// ---------------------------------------------------------------------------
__global__ __launch_bounds__(256) void epilogue_kernel(
    const float* __restrict__ xs_g, const float* __restrict__ xv_g,
    const _Float16* __restrict__ f0p, const _Float16* __restrict__ G,
    const float* __restrict__ w0, const float* __restrict__ w1o,
    const float* __restrict__ w1e, const float* __restrict__ w2e,
    float* __restrict__ out) {
  __shared__ float xs[8][64];
  __shared__ float xv[8][96];
  __shared__ _Float16 gated0[8][KP];
  const int t = threadIdx.x;
  const size_t n0 = (size_t)blockIdx.x * 8;

  for (int idx = t; idx < 8 * 64; idx += 256)
    xs[idx >> 6][idx & 63] = xs_g[(n0 + (idx >> 6)) * 64 + (idx & 63)];
  for (int idx = t; idx < 8 * 96; idx += 256)
    xv[idx / 96][idx % 96] = xv_g[(n0 + idx / 96) * 96 + idx % 96];
  for (int idx = t; idx < 8 * KP; idx += 256) {
    int r = idx / KP, k = idx - r * KP;
    float f = (float)f0p[(n0 + r) * KP + k];
    float g = (k < M0C) ? (float)G[(n0 + r) * NP2 + k] : 0.f;
    gated0[r][k] = (_Float16)(f * g);
  }
  __syncthreads();

  // ---- o0: (f0*g0) @ w0  (64 outs) ----
  {
    const int o = t & 63, rg = t >> 6;
    float a0 = 0.f, a1 = 0.f;
    for (int k = 0; k < M0C; ++k) {
      float w = w0[k * 64 + o];
      a0 += (float)gated0[rg][k] * w;
      a1 += (float)gated0[rg + 4][k] * w;
    }
    out[(n0 + rg) * 288 + o] = a0;
    out[(n0 + rg + 4) * 288 + o] = a1;
  }

  // ---- o1: f1 = [x_v | x_s outer x_v] gated by g1, @ w1o (32 outs x 3) ----
  {
    const int o = t & 31, r = t >> 5;
    float a0 = 0.f, a1 = 0.f, a2 = 0.f;
    const _Float16* Gr = G + (n0 + r) * NP2 + M0C;
    for (int c = 0; c < 32; ++c) {
      float gw = (float)Gr[c] * w1o[c * 32 + o];
      a0 += xv[r][c * 3 + 0] * gw;
      a1 += xv[r][c * 3 + 1] * gw;
      a2 += xv[r][c * 3 + 2] * gw;
    }
    for (int s = 0; s < 64; ++s) {
      float xsv = xs[r][s];
      for (int v = 0; v < 32; ++v) {
        int c = 32 + s * 32 + v;
        float gw = (float)Gr[c] * w1o[c * 32 + o] * xsv;
        a0 += xv[r][v * 3 + 0] * gw;
        a1 += xv[r][v * 3 + 1] * gw;
        a2 += xv[r][v * 3 + 2] * gw;
      }
    }
    float* orow = out + (n0 + r) * 288 + 64;
    orow[o * 3 + 0] = a0;
    orow[o * 3 + 1] = a1;
    orow[o * 3 + 2] = a2;
  }

  // ---- o1e: cross products (k=1 pairs), gated by g1e, @ w1e (16 x 3) ----
  if (t < 128) {
    const int o = t & 15, r = t >> 4;
    float a0 = 0.f, a1 = 0.f, a2 = 0.f;
    const _Float16* Gr = G + (n0 + r) * NP2 + (M0C + M1C);
    int p = 0;
    for (int a = 0; a < 31; ++a) {
      float ax = xv[r][a * 3], ay = xv[r][a * 3 + 1], az = xv[r][a * 3 + 2];
      for (int b = a + 1; b < 32; ++b, ++p) {
        float bx = xv[r][b * 3], by = xv[r][b * 3 + 1], bz = xv[r][b * 3 + 2];
        float gw = (float)Gr[p] * w1e[p * 16 + o] * 0.70710678118654752f;
        a0 += (ay * bz - az * by) * gw;
        a1 += (az * bx - ax * bz) * gw;
        a2 += (ax * by - ay * bx) * gw;
      }
    }
    float* orow = out + (n0 + r) * 288 + 160;
    orow[o * 3 + 0] = a0;
    orow[o * 3 + 1] = a1;
    orow[o * 3 + 2] = a2;
  }

  // ---- o2: symmetric traceless pair features, gated by g2, @ w2e (16 x 5) ----
  if (t < 128) {
    const int o = t & 15, r = t >> 4;
    float m0 = 0.f, m1 = 0.f, m2 = 0.f, m3 = 0.f, m4 = 0.f;
    const _Float16* Gr = G + (n0 + r) * NP2 + (M0C + M1C + A1C);
    const float s2 = 0.70710678118654752f, s6 = 0.40824829046386302f;
    int p = 0;
    for (int a = 0; a < 32; ++a) {
      float ax = xv[r][a * 3], ay = xv[r][a * 3 + 1], az = xv[r][a * 3 + 2];
      for (int b = a; b < 32; ++b, ++p) {
        float bx = xv[r][b * 3], by = xv[r][b * 3 + 1], bz = xv[r][b * 3 + 2];
        float c1 = (b == a) ? s2 : 1.f;
        float gw = (float)Gr[p] * w2e[p * 16 + o] * c1;
        m0 += s2 * (ax * by + ay * bx) * gw;
        m1 += s2 * (ay * bz + az * by) * gw;
        m2 += s2 * (ax * bz + az * bx) * gw;
        m3 += s2 * (ax * bx - ay * by) * gw;
        m4 += s6 * (2.f * az * bz - ax * bx - ay * by) * gw;
      }
    }
    float* orow = out + (n0 + r) * 288 + 208;
    orow[o * 5 + 0] = m0;
    orow[o * 5 + 1] = m1;
    orow[o * 5 + 2] = m2;
    orow[o * 5 + 3] = m3;
    orow[o * 5 + 4] = m4;
  }
}

// ---------------------------------------------------------------------------
extern "C" void kernel_launch(void* const* d_in, const int* in_sizes, int n_in,
                              void* d_out, int out_size, void* d_ws, size_t ws_size,
                              hipStream_t stream) {
  const float* xs  = (const float*)d_in[0];
  const float* xv  = (const float*)d_in[1];
  const float* w1  = (const float*)d_in[2];
  const float* w2  = (const float*)d_in[3];
  const float* w0  = (const float*)d_in[4];
  const float* w1o = (const float*)d_in[5];
  const float* w1e = (const float*)d_in[6];
  const float* w2e = (const float*)d_in[7];
  float* out = (float*)d_out;

  char* ws = (char*)d_ws;
  size_t off = 0;
  _Float16* w1T = (_Float16*)(ws + off); off += (size_t)KP * KP * 2;      // 14.45 MB
  _Float16* w2T = (_Float16*)(ws + off); off += (size_t)NP2 * KP * 2;     // 31.65 MB
  _Float16* f0p = (_Float16*)(ws + off); off += (size_t)N_ROWS * KP * 2;  // 44.04 MB
  _Float16* H   = (_Float16*)(ws + off); off += (size_t)N_ROWS * KP * 2;  // 44.04 MB
  _Float16* G   = (_Float16*)(ws + off);                                  // 96.47 MB
  // total ~230.7 MB

  transpose_cvt_kernel<<<dim3(KP / 32, KP / 32), 256, 0, stream>>>(w1, w1T, M0C, M0C, KP);
  transpose_cvt_kernel<<<dim3(KP / 32, NP2 / 32), 256, 0, stream>>>(w2, w2T, M0C, NIR, KP);
  build_f0_kernel<<<N_ROWS, 256, 0, stream>>>(xs, xv, f0p);
  gemm_kernel<true><<<dim3(KP / 128, N_ROWS / 128), 256, 0, stream>>>(f0p, w1T, H, KP, KP, KP, KP);
  gemm_kernel<false><<<dim3(NP2 / 128, N_ROWS / 128), 256, 0, stream>>>(H, w2T, G, KP, KP, KP, NP2);
  epilogue_kernel<<<N_ROWS / 8, 256, 0, stream>>>(xs, xv, f0p, G, w0, w1o, w1e, w2e, out);
}

// Round 2
// 931.588 us; speedup vs baseline: 2.1362x; 2.1362x over previous
//
#include <hip/hip_runtime.h>
#include <hip/hip_bf16.h>
#include <stdint.h>

// Problem constants
#define N_ROWS 8192
#define M0C 2672    // C0 + P0 + P1 = 64 + 2080 + 528
#define M1C 2080    // C1 + C0*C1
#define A1C 496
#define P1C 528
#define KP  2688    // M0 padded to multiple of 128 (and 32 for K)
#define NP2 5888    // NUM_IRREPS (5776) padded to multiple of 128
#define NIR 5776

typedef __attribute__((ext_vector_type(8))) _Float16 half8;
typedef __attribute__((ext_vector_type(4))) float floatx4;

__device__ __forceinline__ void async_copy16(const _Float16* g, _Float16* l) {
  __builtin_amdgcn_global_load_lds(
      (__attribute__((address_space(1))) void*)(g),
      (__attribute__((address_space(3))) void*)(l), 16, 0, 0);
}

// ---------------------------------------------------------------------------
// Transpose + fp32->fp16 convert with zero padding.
// dst[r][c] = (c < srcR && r < srcC) ? src[c][r] : 0;  dst is [dstR][dstC(ld)]
// grid: x = dstC/32, y = dstR/32
// ---------------------------------------------------------------------------
__global__ __launch_bounds__(256) void transpose_cvt_kernel(
    const float* __restrict__ src, _Float16* __restrict__ dst,
    int srcR, int srcC, int dstC) {
  __shared__ float tile[32][33];
  const int t = threadIdx.x, tx = t & 31, ty = t >> 5;
  const int bx = blockIdx.x, by = blockIdx.y;
#pragma unroll
  for (int i = 0; i < 4; ++i) {
    int sr = bx * 32 + ty + i * 8;   // src row (k dim)
    int sc = by * 32 + tx;           // src col
    tile[ty + i * 8][tx] = (sr < srcR && sc < srcC) ? src[(size_t)sr * srcC + sc] : 0.f;
  }
  __syncthreads();
#pragma unroll
  for (int i = 0; i < 4; ++i) {
    int dr = by * 32 + ty + i * 8;
    int dc = bx * 32 + tx;
    dst[(size_t)dr * dstC + dc] = (_Float16)tile[tx][ty + i * 8];
  }
}

// ---------------------------------------------------------------------------
// triu_indices(C) pair decode: p -> (a, b), b >= a.
// ---------------------------------------------------------------------------
__device__ __forceinline__ void triu_ab(int p, int C, int& a, int& b) {
  float fC = (float)C + 0.5f;
  int ai = (int)(fC - sqrtf(fC * fC - 2.0f * (float)p));
  if (ai < 0) ai = 0;
  while (ai > 0 && ai * C - ai * (ai - 1) / 2 > p) --ai;
  while ((ai + 1) * C - (ai + 1) * ai / 2 <= p) ++ai;
  a = ai;
  b = p - (ai * C - ai * (ai - 1) / 2) + ai;
}

// ---------------------------------------------------------------------------
// f0 = [x_s (64) | ss (2080) | vv0 (528) | zero pad (16)]  as fp16 [N][KP]
// ---------------------------------------------------------------------------
__global__ __launch_bounds__(256) void build_f0_kernel(
    const float* __restrict__ xs_g, const float* __restrict__ xv_g,
    _Float16* __restrict__ f0p) {
  __shared__ float xs[64];
  __shared__ float xv[96];
  const int t = threadIdx.x;
  const size_t n = blockIdx.x;
  if (t < 64) xs[t] = xs_g[n * 64 + t];
  else if (t < 160) xv[t - 64] = xv_g[n * 96 + (t - 64)];
  __syncthreads();
  for (int c = t; c < KP; c += 256) {
    float v;
    if (c < 64) {
      v = xs[c];
    } else if (c < 2144) {                       // ss: pair products of x_s
      int a, b;
      triu_ab(c - 64, 64, a, b);
      v = xs[a] * xs[b] * ((a == b) ? 0.70710678118654752f : 1.f);
    } else if (c < M0C) {                        // vv0: pair dots of x_v
      int a, b;
      triu_ab(c - 2144, 32, a, b);
      float d = xv[a * 3] * xv[b * 3] + xv[a * 3 + 1] * xv[b * 3 + 1] +
                xv[a * 3 + 2] * xv[b * 3 + 2];
      v = d * ((a == b) ? 0.70710678118654752f : 1.f) * 0.57735026918962576f;
    } else {
      v = 0.f;                                   // pad
    }
    f0p[n * KP + c] = (_Float16)v;
  }
}

// ---------------------------------------------------------------------------
// fp16 MFMA GEMM, m97 structure (128x128 tile, BK=32, global_load_lds w16).
// A: [rows][K] fp16, B: [cols][K] fp16 (math-B transposed), C: [rows][ldc].
// ---------------------------------------------------------------------------
template <bool SILU>
__global__ __launch_bounds__(256, 3) void gemm_kernel(
    const _Float16* __restrict__ A, const _Float16* __restrict__ B,
    _Float16* __restrict__ C, int K, int lda, int ldb, int ldc) {
  __shared__ alignas(16) _Float16 As[128 * 32];
  __shared__ alignas(16) _Float16 Bs[128 * 32];
  const int tid = threadIdx.x;
  const size_t row0 = (size_t)blockIdx.y * 128;
  const size_t col0 = (size_t)blockIdx.x * 128;

  const _Float16* ga[2];
  const _Float16* gb[2];
  _Float16* la[2];
  _Float16* lb[2];
#pragma unroll
  for (int i = 0; i < 2; ++i) {
    int c = tid + i * 256;
    int r = c >> 2, kc = (c & 3) * 8;
    ga[i] = A + (row0 + r) * lda + kc;
    gb[i] = B + (col0 + r) * ldb + kc;
    la[i] = &As[c * 8];
    lb[i] = &Bs[c * 8];
  }

  const int lane = tid & 63;
  const int wave = tid >> 6;
  const int wm = (wave & 1) * 64;
  const int wn = (wave >> 1) * 64;
  const int m16 = lane & 15;
  const int quad = lane >> 4;
  int aoff[4], boff[4];
#pragma unroll
  for (int i = 0; i < 4; ++i) {
    aoff[i] = (wm + i * 16 + m16) * 32 + quad * 8;
    boff[i] = (wn + i * 16 + m16) * 32 + quad * 8;
  }

  floatx4 acc[4][4] = {};

  for (int k = 0; k < K; k += 32) {
    if (k) __syncthreads();
#pragma unroll
    for (int i = 0; i < 2; ++i) {
      async_copy16(ga[i] + k, la[i]);
      async_copy16(gb[i] + k, lb[i]);
    }
    __syncthreads();

    half8 af[4], bf[4];
#pragma unroll
    for (int i = 0; i < 4; ++i) af[i] = *(const half8*)&As[aoff[i]];
#pragma unroll
    for (int j = 0; j < 4; ++j) bf[j] = *(const half8*)&Bs[boff[j]];
#pragma unroll
    for (int i = 0; i < 4; ++i)
#pragma unroll
      for (int j = 0; j < 4; ++j)
        acc[i][j] = __builtin_amdgcn_mfma_f32_16x16x32_f16(af[i], bf[j], acc[i][j], 0, 0, 0);
  }

  // C/D layout: col = lane&15, row = quad*4 + reg
#pragma unroll
  for (int i = 0; i < 4; ++i) {
    size_t r = row0 + wm + i * 16 + quad * 4;
#pragma unroll
    for (int j = 0; j < 4; ++j) {
      size_t cc = col0 + wn + j * 16 + m16;
#pragma unroll
      for (int rr = 0; rr < 4; ++rr) {
        float v = acc[i][j][rr];
        if (SILU) v = v / (1.f + __expf(-v));
        C[(r + rr) * ldc + cc] = (_Float16)v;
      }
    }
  }
}

// ---------------------------------------------------------------------------
// epi0: o0 = (f0 .* g0) @ w0.  16 rows/block, K=2688, N=64. grid 512.
// ---------------------------------------------------------------------------
__global__ __launch_bounds__(256) void epi0_kernel(
    const _Float16* __restrict__ f0p, const _Float16* __restrict__ G,
    const _Float16* __restrict__ w0T, float* __restrict__ out) {
  __shared__ alignas(16) _Float16 As[16 * 32];
  const int t = threadIdx.x;
  const size_t n0 = (size_t)blockIdx.x * 16;
  const int lane = t & 63, wave = t >> 6;
  const int m16 = lane & 15, quad = lane >> 4;
  const int br = t >> 2, bc8 = (t & 3) * 8;   // build map (t < 64)

  floatx4 acc = {};
  for (int k0 = 0; k0 < KP; k0 += 32) {
    if (k0) __syncthreads();
    if (t < 64) {
      half8 f = *(const half8*)&f0p[(n0 + br) * KP + k0 + bc8];
      half8 g = *(const half8*)&G[(n0 + br) * NP2 + k0 + bc8];
      half8 a;
#pragma unroll
      for (int j = 0; j < 8; ++j) a[j] = (_Float16)((float)f[j] * (float)g[j]);
      *(half8*)&As[br * 32 + bc8] = a;
    }
    __syncthreads();
    half8 af = *(const half8*)&As[m16 * 32 + quad * 8];
    half8 bf = *(const half8*)&w0T[(size_t)(wave * 16 + m16) * KP + k0 + quad * 8];
    acc = __builtin_amdgcn_mfma_f32_16x16x32_f16(af, bf, acc, 0, 0, 0);
  }
#pragma unroll
  for (int rr = 0; rr < 4; ++rr)
    out[(n0 + quad * 4 + rr) * 288 + wave * 16 + m16] = acc[rr];
}

// ---------------------------------------------------------------------------
// epi1: o1[n][o][i] = sum_c f1[n][c][i]*g1[n][c]*w1o[c][o].
// f1[c<32] = xv[c][i]; f1[c>=32] = xs[s]*xv[v][i], s=(c-32)/32 (uniform per
// 32-wide K-step!), v=(c-32)%32.  32 rows/block, K=2080, N=32. grid 256.
// ---------------------------------------------------------------------------
__global__ __launch_bounds__(256) void epi1_kernel(
    const float* __restrict__ xs_g, const float* __restrict__ xv_g,
    const _Float16* __restrict__ G, const _Float16* __restrict__ w1oT,
    float* __restrict__ out) {
  __shared__ float xs[32][64];
  __shared__ float xv[32][96];
  __shared__ alignas(16) _Float16 As[3][32 * 32];
  const int t = threadIdx.x;
  const size_t n0 = (size_t)blockIdx.x * 32;
  for (int idx = t; idx < 32 * 64; idx += 256)
    xs[idx >> 6][idx & 63] = xs_g[(n0 + (idx >> 6)) * 64 + (idx & 63)];
  for (int idx = t; idx < 32 * 96; idx += 256)
    xv[idx / 96][idx % 96] = xv_g[(n0 + idx / 96) * 96 + idx % 96];
  const int lane = t & 63, wave = t >> 6;
  const int m16 = lane & 15, quad = lane >> 4;
  const int rt = (wave & 1) * 16;   // row tile
  const int nt = (wave >> 1) * 16;  // col tile
  const int br = t >> 2, bc8 = (t & 3) * 8;   // build map (t < 128)

  floatx4 acc[3] = {};
  __syncthreads();
  for (int k0 = 0; k0 < 2080; k0 += 32) {
    if (k0) __syncthreads();
    if (t < 128) {
      half8 g8 = *(const half8*)&G[(n0 + br) * NP2 + M0C + k0 + bc8];
      half8 a0, a1, a2;
      if (k0 == 0) {
#pragma unroll
        for (int j = 0; j < 8; ++j) {
          float g = (float)g8[j];
          int v = bc8 + j;
          a0[j] = (_Float16)(xv[br][v * 3 + 0] * g);
          a1[j] = (_Float16)(xv[br][v * 3 + 1] * g);
          a2[j] = (_Float16)(xv[br][v * 3 + 2] * g);
        }
      } else {
        float xsr = xs[br][(k0 - 32) >> 5];
#pragma unroll
        for (int j = 0; j < 8; ++j) {
          float g = (float)g8[j] * xsr;
          int v = bc8 + j;
          a0[j] = (_Float16)(xv[br][v * 3 + 0] * g);
          a1[j] = (_Float16)(xv[br][v * 3 + 1] * g);
          a2[j] = (_Float16)(xv[br][v * 3 + 2] * g);
        }
      }
      *(half8*)&As[0][br * 32 + bc8] = a0;
      *(half8*)&As[1][br * 32 + bc8] = a1;
      *(half8*)&As[2][br * 32 + bc8] = a2;
    }
    __syncthreads();
    half8 bf = *(const half8*)&w1oT[(size_t)(nt + m16) * 2080 + k0 + quad * 8];
#pragma unroll
    for (int i = 0; i < 3; ++i) {
      half8 af = *(const half8*)&As[i][(rt + m16) * 32 + quad * 8];
      acc[i] = __builtin_amdgcn_mfma_f32_16x16x32_f16(af, bf, acc[i], 0, 0, 0);
    }
  }
#pragma unroll
  for (int i = 0; i < 3; ++i)
#pragma unroll
    for (int rr = 0; rr < 4; ++rr)
      out[(n0 + rt + quad * 4 + rr) * 288 + 64 + (nt + m16) * 3 + i] = acc[i][rr];
}

// ---------------------------------------------------------------------------
// epi1e2: o1e (cross pairs, K=496->512, N=16, 3 comps) then
//         o2  (sym pairs,   K=528->544, N=16, 5 comps).  64 rows/block, grid 128.
// ---------------------------------------------------------------------------
__global__ __launch_bounds__(256) void epi1e2_kernel(
    const float* __restrict__ xv_g, const _Float16* __restrict__ G,
    const _Float16* __restrict__ w1eT, const _Float16* __restrict__ w2eT,
    float* __restrict__ out) {
  __shared__ float xv[64][96];
  __shared__ alignas(16) _Float16 As[5][64 * 32];
  __shared__ uint8_t ea[512], eb[512], sa[544], sb[544];
  const int t = threadIdx.x;
  const size_t n0 = (size_t)blockIdx.x * 64;
  for (int idx = t; idx < 64 * 96; idx += 256)
    xv[idx / 96][idx % 96] = xv_g[(n0 + idx / 96) * 96 + idx % 96];
  for (int p = t; p < 512; p += 256) {
    int a = 0, b = 0;
    if (p < A1C) { triu_ab(p, 31, a, b); b += 1; }
    ea[p] = (uint8_t)a; eb[p] = (uint8_t)b;
  }
  for (int p = t; p < 544; p += 256) {
    int a = 0, b = 0;
    if (p < P1C) triu_ab(p, 32, a, b);
    sa[p] = (uint8_t)a; sb[p] = (uint8_t)b;
  }
  const int lane = t & 63, wave = t >> 6;
  const int m16 = lane & 15, quad = lane >> 4;
  const int br = t >> 2, bc8 = (t & 3) * 8;   // build map (all 256 threads)
  const float s2 = 0.70710678118654752f, s6 = 0.40824829046386302f;

  // ---- phase 1: o1e ----
  {
    floatx4 acc[3] = {};
    for (int k0 = 0; k0 < 512; k0 += 32) {
      __syncthreads();
      {
        half8 g8 = *(const half8*)&G[(n0 + br) * NP2 + (M0C + M1C) + k0 + bc8];
        half8 a0, a1, a2;
#pragma unroll
        for (int j = 0; j < 8; ++j) {
          int p = k0 + bc8 + j;
          if (p < A1C) {
            int a = ea[p], b = eb[p];
            float ax = xv[br][a * 3], ay = xv[br][a * 3 + 1], az = xv[br][a * 3 + 2];
            float bx = xv[br][b * 3], by = xv[br][b * 3 + 1], bz = xv[br][b * 3 + 2];
            float g = (float)g8[j] * s2;
            a0[j] = (_Float16)((ay * bz - az * by) * g);
            a1[j] = (_Float16)((az * bx - ax * bz) * g);
            a2[j] = (_Float16)((ax * by - ay * bx) * g);
          } else {
            a0[j] = (_Float16)0.f; a1[j] = (_Float16)0.f; a2[j] = (_Float16)0.f;
          }
        }
        *(half8*)&As[0][br * 32 + bc8] = a0;
        *(half8*)&As[1][br * 32 + bc8] = a1;
        *(half8*)&As[2][br * 32 + bc8] = a2;
      }
      __syncthreads();
      half8 bf = *(const half8*)&w1eT[(size_t)m16 * 512 + k0 + quad * 8];
#pragma unroll
      for (int i = 0; i < 3; ++i) {
        half8 af = *(const half8*)&As[i][(wave * 16 + m16) * 32 + quad * 8];
        acc[i] = __builtin_amdgcn_mfma_f32_16x16x32_f16(af, bf, acc[i], 0, 0, 0);
      }
    }
#pragma unroll
    for (int i = 0; i < 3; ++i)
#pragma unroll
      for (int rr = 0; rr < 4; ++rr)
        out[(n0 + wave * 16 + quad * 4 + rr) * 288 + 160 + m16 * 3 + i] = acc[i][rr];
  }

  // ---- phase 2: o2 ----
  {
    floatx4 acc[5] = {};
    for (int k0 = 0; k0 < 544; k0 += 32) {
      __syncthreads();
      {
        half8 g8 = *(const half8*)&G[(n0 + br) * NP2 + (M0C + M1C + A1C) + k0 + bc8];
        half8 m0v, m1v, m2v, m3v, m4v;
#pragma unroll
        for (int j = 0; j < 8; ++j) {
          int p = k0 + bc8 + j;
          if (p < P1C) {
            int a = sa[p], b = sb[p];
            float ax = xv[br][a * 3], ay = xv[br][a * 3 + 1], az = xv[br][a * 3 + 2];
            float bx = xv[br][b * 3], by = xv[br][b * 3 + 1], bz = xv[br][b * 3 + 2];
            float c1 = (a == b) ? s2 : 1.f;
            float gw = (float)g8[j] * c1;
            m0v[j] = (_Float16)(s2 * (ax * by + ay * bx) * gw);
            m1v[j] = (_Float16)(s2 * (ay * bz + az * by) * gw);
            m2v[j] = (_Float16)(s2 * (ax * bz + az * bx) * gw);
            m3v[j] = (_Float16)(s2 * (ax * bx - ay * by) * gw);
            m4v[j] = (_Float16)(s6 * (2.f * az * bz - ax * bx - ay * by) * gw);
          } else {
            m0v[j] = (_Float16)0.f; m1v[j] = (_Float16)0.f; m2v[j] = (_Float16)0.f;
            m3v[j] = (_Float16)0.f; m4v[j] = (_Float16)0.f;
          }
        }
        *(half8*)&As[0][br * 32 + bc8] = m0v;
        *(half8*)&As[1][br * 32 + bc8] = m1v;
        *(half8*)&As[2][br * 32 + bc8] = m2v;
        *(half8*)&As[3][br * 32 + bc8] = m3v;
        *(half8*)&As[4][br * 32 + bc8] = m4v;
      }
      __syncthreads();
      half8 bf = *(const half8*)&w2eT[(size_t)m16 * 544 + k0 + quad * 8];
#pragma unroll
      for (int m = 0; m < 5; ++m) {
        half8 af = *(const half8*)&As[m][(wave * 16 + m16) * 32 + quad * 8];
        acc[m] = __builtin_amdgcn_mfma_f32_16x16x32_f16(af, bf, acc[m], 0, 0, 0);
      }
    }
#pragma unroll
    for (int m = 0; m < 5; ++m)
#pragma unroll
      for (int rr = 0; rr < 4; ++rr)
        out[(n0 + wave * 16 + quad * 4 + rr) * 288 + 208 + m16 * 5 + m] = acc[m][rr];
  }
}

// ---------------------------------------------------------------------------
extern "C" void kernel_launch(void* const* d_in, const int* in_sizes, int n_in,
                              void* d_out, int out_size, void* d_ws, size_t ws_size,
                              hipStream_t stream) {
  const float* xs  = (const float*)d_in[0];
  const float* xv  = (const float*)d_in[1];
  const float* w1  = (const float*)d_in[2];
  const float* w2  = (const float*)d_in[3];
  const float* w0  = (const float*)d_in[4];
  const float* w1o = (const float*)d_in[5];
  const float* w1e = (const float*)d_in[6];
  const float* w2e = (const float*)d_in[7];
  float* out = (float*)d_out;

  char* ws = (char*)d_ws;
  size_t off = 0;
  _Float16* w1T = (_Float16*)(ws + off); off += (size_t)KP * KP * 2;      // 14.45 MB
  _Float16* w2T = (_Float16*)(ws + off); off += (size_t)NP2 * KP * 2;     // 31.65 MB
  _Float16* f0p = (_Float16*)(ws + off); off += (size_t)N_ROWS * KP * 2;  // 44.04 MB
  _Float16* H   = (_Float16*)(ws + off); off += (size_t)N_ROWS * KP * 2;  // 44.04 MB
  _Float16* G   = (_Float16*)(ws + off);                                  // 96.47 MB
  // total ~230.7 MB (same as round 0)

  // Small epilogue weights live inside w1T's region (dead after GEMM1).
  _Float16* w0T  = w1T;                                     // 64  x 2688 = 344064 B
  _Float16* w1oT = (_Float16*)((char*)w1T + 344064);        // 32  x 2080 = 133120 B
  _Float16* w1eT = (_Float16*)((char*)w1T + 477184);        // 32  x 512  =  32768 B
  _Float16* w2eT = (_Float16*)((char*)w1T + 509952);        // 32  x 544  =  34816 B

  transpose_cvt_kernel<<<dim3(KP / 32, KP / 32), 256, 0, stream>>>(w1, w1T, M0C, M0C, KP);
  transpose_cvt_kernel<<<dim3(KP / 32, NP2 / 32), 256, 0, stream>>>(w2, w2T, M0C, NIR, KP);
  build_f0_kernel<<<N_ROWS, 256, 0, stream>>>(xs, xv, f0p);
  gemm_kernel<true><<<dim3(KP / 128, N_ROWS / 128), 256, 0, stream>>>(f0p, w1T, H, KP, KP, KP, KP);
  // w1T now dead -> overwrite with epilogue weights
  transpose_cvt_kernel<<<dim3(KP / 32, 2), 256, 0, stream>>>(w0, w0T, M0C, 64, KP);
  transpose_cvt_kernel<<<dim3(65, 1), 256, 0, stream>>>(w1o, w1oT, M1C, 32, 2080);
  transpose_cvt_kernel<<<dim3(16, 1), 256, 0, stream>>>(w1e, w1eT, A1C, 16, 512);
  transpose_cvt_kernel<<<dim3(17, 1), 256, 0, stream>>>(w2e, w2eT, P1C, 16, 544);
  gemm_kernel<false><<<dim3(NP2 / 128, N_ROWS / 128), 256, 0, stream>>>(H, w2T, G, KP, KP, KP, NP2);
  epi0_kernel<<<512, 256, 0, stream>>>(f0p, G, w0T, out);
  epi1_kernel<<<256, 256, 0, stream>>>(xs, xv, G, w1oT, out);
  epi1e2_kernel<<<128, 256, 0, stream>>>(xv, G, w1eT, w2eT, out);
}

// Round 3
// 898.972 us; speedup vs baseline: 2.2137x; 1.0363x over previous
//
#include <hip/hip_runtime.h>
#include <hip/hip_bf16.h>
#include <stdint.h>

// Problem constants
#define N_ROWS 8192
#define M0C 2672    // C0 + P0 + P1 = 64 + 2080 + 528
#define M1C 2080    // C1 + C0*C1
#define A1C 496
#define P1C 528
#define KP  2688    // M0 padded to multiple of 128 (and 32 for K)
#define NP2 5888    // NUM_IRREPS (5776) padded to multiple of 128
#define NIR 5776

typedef __attribute__((ext_vector_type(8))) _Float16 half8;
typedef __attribute__((ext_vector_type(4))) float floatx4;

__device__ __forceinline__ void async_copy16(const _Float16* g, _Float16* l) {
  __builtin_amdgcn_global_load_lds(
      (__attribute__((address_space(1))) void*)(g),
      (__attribute__((address_space(3))) void*)(l), 16, 0, 0);
}

// LDS swizzle: LDS[row][col] holds global k-chunk col ^ ((row>>1)&3) of row.
// Writers with lane-contiguous dest (global_load_lds) permute the SOURCE chunk;
// readers xor the chunk index. Makes ds_read_b128 bank-conflict-free
// (bank-quad = (4r + sw) mod 8 is a permutation within each 8-lane group).

// ---------------------------------------------------------------------------
// Transpose + fp32->fp16 convert with zero padding.
// ---------------------------------------------------------------------------
__global__ __launch_bounds__(256) void transpose_cvt_kernel(
    const float* __restrict__ src, _Float16* __restrict__ dst,
    int srcR, int srcC, int dstC) {
  __shared__ float tile[32][33];
  const int t = threadIdx.x, tx = t & 31, ty = t >> 5;
  const int bx = blockIdx.x, by = blockIdx.y;
#pragma unroll
  for (int i = 0; i < 4; ++i) {
    int sr = bx * 32 + ty + i * 8;   // src row (k dim)
    int sc = by * 32 + tx;           // src col
    tile[ty + i * 8][tx] = (sr < srcR && sc < srcC) ? src[(size_t)sr * srcC + sc] : 0.f;
  }
  __syncthreads();
#pragma unroll
  for (int i = 0; i < 4; ++i) {
    int dr = by * 32 + ty + i * 8;
    int dc = bx * 32 + tx;
    dst[(size_t)dr * dstC + dc] = (_Float16)tile[tx][ty + i * 8];
  }
}

// ---------------------------------------------------------------------------
// triu_indices(C) pair decode: p -> (a, b), b >= a.
// ---------------------------------------------------------------------------
__device__ __forceinline__ void triu_ab(int p, int C, int& a, int& b) {
  float fC = (float)C + 0.5f;
  int ai = (int)(fC - sqrtf(fC * fC - 2.0f * (float)p));
  if (ai < 0) ai = 0;
  while (ai > 0 && ai * C - ai * (ai - 1) / 2 > p) --ai;
  while ((ai + 1) * C - (ai + 1) * ai / 2 <= p) ++ai;
  a = ai;
  b = p - (ai * C - ai * (ai - 1) / 2) + ai;
}

// ---------------------------------------------------------------------------
// f0 = [x_s (64) | ss (2080) | vv0 (528) | zero pad (16)]  as fp16 [N][KP]
// ---------------------------------------------------------------------------
__global__ __launch_bounds__(256) void build_f0_kernel(
    const float* __restrict__ xs_g, const float* __restrict__ xv_g,
    _Float16* __restrict__ f0p) {
  __shared__ float xs[64];
  __shared__ float xv[96];
  const int t = threadIdx.x;
  const size_t n = blockIdx.x;
  if (t < 64) xs[t] = xs_g[n * 64 + t];
  else if (t < 160) xv[t - 64] = xv_g[n * 96 + (t - 64)];
  __syncthreads();
  for (int c = t; c < KP; c += 256) {
    float v;
    if (c < 64) {
      v = xs[c];
    } else if (c < 2144) {                       // ss: pair products of x_s
      int a, b;
      triu_ab(c - 64, 64, a, b);
      v = xs[a] * xs[b] * ((a == b) ? 0.70710678118654752f : 1.f);
    } else if (c < M0C) {                        // vv0: pair dots of x_v
      int a, b;
      triu_ab(c - 2144, 32, a, b);
      float d = xv[a * 3] * xv[b * 3] + xv[a * 3 + 1] * xv[b * 3 + 1] +
                xv[a * 3 + 2] * xv[b * 3 + 2];
      v = d * ((a == b) ? 0.70710678118654752f : 1.f) * 0.57735026918962576f;
    } else {
      v = 0.f;                                   // pad
    }
    f0p[n * KP + c] = (_Float16)v;
  }
}

// ---------------------------------------------------------------------------
// fp16 MFMA GEMM, m97 structure + swizzled LDS (conflict-free ds_read_b128).
// A: [rows][K] fp16, B: [cols][K] fp16 (math-B transposed), C: [rows][ldc].
// ---------------------------------------------------------------------------
template <bool SILU>
__global__ __launch_bounds__(256, 3) void gemm_kernel(
    const _Float16* __restrict__ A, const _Float16* __restrict__ B,
    _Float16* __restrict__ C, int K, int lda, int ldb, int ldc) {
  __shared__ alignas(16) _Float16 As[128 * 32];
  __shared__ alignas(16) _Float16 Bs[128 * 32];
  const int tid = threadIdx.x;
  const size_t row0 = (size_t)blockIdx.y * 128;
  const size_t col0 = (size_t)blockIdx.x * 128;

  const _Float16* ga[2];
  const _Float16* gb[2];
  _Float16* la[2];
  _Float16* lb[2];
#pragma unroll
  for (int i = 0; i < 2; ++i) {
    int c = tid + i * 256;
    int r = c >> 2;
    int scol = (c & 3) ^ ((r >> 1) & 3);   // swizzled source chunk
    ga[i] = A + (row0 + r) * lda + scol * 8;
    gb[i] = B + (col0 + r) * ldb + scol * 8;
    la[i] = &As[c * 8];                    // LDS dest stays lane-contiguous
    lb[i] = &Bs[c * 8];
  }

  const int lane = tid & 63;
  const int wave = tid >> 6;
  const int wm = (wave & 1) * 64;
  const int wn = (wave >> 1) * 64;
  const int m16 = lane & 15;
  const int quad = lane >> 4;
  const int sw8 = (quad ^ ((m16 >> 1) & 3)) * 8;  // swizzled read chunk
  int aoff[4], boff[4];
#pragma unroll
  for (int i = 0; i < 4; ++i) {
    aoff[i] = (wm + i * 16 + m16) * 32 + sw8;
    boff[i] = (wn + i * 16 + m16) * 32 + sw8;
  }

  floatx4 acc[4][4] = {};

  for (int k = 0; k < K; k += 32) {
    if (k) __syncthreads();
#pragma unroll
    for (int i = 0; i < 2; ++i) {
      async_copy16(ga[i] + k, la[i]);
      async_copy16(gb[i] + k, lb[i]);
    }
    __syncthreads();

    half8 af[4], bf[4];
#pragma unroll
    for (int i = 0; i < 4; ++i) af[i] = *(const half8*)&As[aoff[i]];
#pragma unroll
    for (int j = 0; j < 4; ++j) bf[j] = *(const half8*)&Bs[boff[j]];
#pragma unroll
    for (int i = 0; i < 4; ++i)
#pragma unroll
      for (int j = 0; j < 4; ++j)
        acc[i][j] = __builtin_amdgcn_mfma_f32_16x16x32_f16(af[i], bf[j], acc[i][j], 0, 0, 0);
  }

  // C/D layout: col = lane&15, row = quad*4 + reg
#pragma unroll
  for (int i = 0; i < 4; ++i) {
    size_t r = row0 + wm + i * 16 + quad * 4;
#pragma unroll
    for (int j = 0; j < 4; ++j) {
      size_t cc = col0 + wn + j * 16 + m16;
#pragma unroll
      for (int rr = 0; rr < 4; ++rr) {
        float v = acc[i][j][rr];
        if (SILU) v = v / (1.f + __expf(-v));
        C[(r + rr) * ldc + cc] = (_Float16)v;
      }
    }
  }
}

// ---------------------------------------------------------------------------
// epi0: o0 = (f0 .* g0) @ w0.  16 rows/block, K=2688, N=64. grid 512.
// ---------------------------------------------------------------------------
__global__ __launch_bounds__(256) void epi0_kernel(
    const _Float16* __restrict__ f0p, const _Float16* __restrict__ G,
    const _Float16* __restrict__ w0T, float* __restrict__ out) {
  __shared__ alignas(16) _Float16 As[16 * 32];
  const int t = threadIdx.x;
  const size_t n0 = (size_t)blockIdx.x * 16;
  const int lane = t & 63, wave = t >> 6;
  const int m16 = lane & 15, quad = lane >> 4;
  const int sw8 = (quad ^ ((m16 >> 1) & 3)) * 8;
  const int br = t >> 2;
  const int bsw8 = ((t & 3) ^ ((br >> 1) & 3)) * 8;  // swizzled build column

  floatx4 acc = {};
  for (int k0 = 0; k0 < KP; k0 += 32) {
    if (k0) __syncthreads();
    if (t < 64) {
      half8 f = *(const half8*)&f0p[(n0 + br) * KP + k0 + bsw8];
      half8 g = *(const half8*)&G[(n0 + br) * NP2 + k0 + bsw8];
      half8 a;
#pragma unroll
      for (int j = 0; j < 8; ++j) a[j] = (_Float16)((float)f[j] * (float)g[j]);
      *(half8*)&As[br * 32 + (t & 3) * 8] = a;
    }
    __syncthreads();
    half8 af = *(const half8*)&As[m16 * 32 + sw8];
    half8 bf = *(const half8*)&w0T[(size_t)(wave * 16 + m16) * KP + k0 + quad * 8];
    acc = __builtin_amdgcn_mfma_f32_16x16x32_f16(af, bf, acc, 0, 0, 0);
  }
#pragma unroll
  for (int rr = 0; rr < 4; ++rr)
    out[(n0 + quad * 4 + rr) * 288 + wave * 16 + m16] = acc[rr];
}

// ---------------------------------------------------------------------------
// epi1: o1[n][o][i] = sum_c f1[n][c][i]*g1[n][c]*w1o[c][o].
// 32 rows/block, K=2080, N=32. grid 256.
// ---------------------------------------------------------------------------
__global__ __launch_bounds__(256) void epi1_kernel(
    const float* __restrict__ xs_g, const float* __restrict__ xv_g,
    const _Float16* __restrict__ G, const _Float16* __restrict__ w1oT,
    float* __restrict__ out) {
  __shared__ float xs[32][64];
  __shared__ float xv[32][96];
  __shared__ alignas(16) _Float16 As[3][32 * 32];
  const int t = threadIdx.x;
  const size_t n0 = (size_t)blockIdx.x * 32;
  for (int idx = t; idx < 32 * 64; idx += 256)
    xs[idx >> 6][idx & 63] = xs_g[(n0 + (idx >> 6)) * 64 + (idx & 63)];
  for (int idx = t; idx < 32 * 96; idx += 256)
    xv[idx / 96][idx % 96] = xv_g[(n0 + idx / 96) * 96 + idx % 96];
  const int lane = t & 63, wave = t >> 6;
  const int m16 = lane & 15, quad = lane >> 4;
  const int sw8 = (quad ^ ((m16 >> 1) & 3)) * 8;
  const int rt = (wave & 1) * 16;   // row tile
  const int nt = (wave >> 1) * 16;  // col tile
  const int br = t >> 2;
  const int bchunk = (t & 3) ^ ((br >> 1) & 3);  // swizzled source chunk
  const int bc8 = bchunk * 8;

  floatx4 acc[3] = {};
  __syncthreads();
  for (int k0 = 0; k0 < 2080; k0 += 32) {
    if (k0) __syncthreads();
    if (t < 128) {
      half8 g8 = *(const half8*)&G[(n0 + br) * NP2 + M0C + k0 + bc8];
      half8 a0, a1, a2;
      if (k0 == 0) {
#pragma unroll
        for (int j = 0; j < 8; ++j) {
          float g = (float)g8[j];
          int v = bc8 + j;
          a0[j] = (_Float16)(xv[br][v * 3 + 0] * g);
          a1[j] = (_Float16)(xv[br][v * 3 + 1] * g);
          a2[j] = (_Float16)(xv[br][v * 3 + 2] * g);
        }
      } else {
        float xsr = xs[br][(k0 - 32) >> 5];
#pragma unroll
        for (int j = 0; j < 8; ++j) {
          float g = (float)g8[j] * xsr;
          int v = bc8 + j;
          a0[j] = (_Float16)(xv[br][v * 3 + 0] * g);
          a1[j] = (_Float16)(xv[br][v * 3 + 1] * g);
          a2[j] = (_Float16)(xv[br][v * 3 + 2] * g);
        }
      }
      *(half8*)&As[0][br * 32 + (t & 3) * 8] = a0;
      *(half8*)&As[1][br * 32 + (t & 3) * 8] = a1;
      *(half8*)&As[2][br * 32 + (t & 3) * 8] = a2;
    }
    __syncthreads();
    half8 bf = *(const half8*)&w1oT[(size_t)(nt + m16) * 2080 + k0 + quad * 8];
#pragma unroll
    for (int i = 0; i < 3; ++i) {
      half8 af = *(const half8*)&As[i][(rt + m16) * 32 + sw8];
      acc[i] = __builtin_amdgcn_mfma_f32_16x16x32_f16(af, bf, acc[i], 0, 0, 0);
    }
  }
#pragma unroll
  for (int i = 0; i < 3; ++i)
#pragma unroll
    for (int rr = 0; rr < 4; ++rr)
      out[(n0 + rt + quad * 4 + rr) * 288 + 64 + (nt + m16) * 3 + i] = acc[i][rr];
}

// ---------------------------------------------------------------------------
// epi1e2: blockIdx.y==0 -> o1e (K=496->512), ==1 -> o2 (K=528->544).
// 64 rows/block, N=16. grid (128, 2).
// ---------------------------------------------------------------------------
__global__ __launch_bounds__(256) void epi1e2_kernel(
    const float* __restrict__ xv_g, const _Float16* __restrict__ G,
    const _Float16* __restrict__ w1eT, const _Float16* __restrict__ w2eT,
    float* __restrict__ out) {
  __shared__ float xv[64][96];
  __shared__ alignas(16) _Float16 As[5][64 * 32];
  __shared__ uint8_t pa[544], pb[544];
  const int t = threadIdx.x;
  const size_t n0 = (size_t)blockIdx.x * 64;
  const int phase = blockIdx.y;
  for (int idx = t; idx < 64 * 96; idx += 256)
    xv[idx / 96][idx % 96] = xv_g[(n0 + idx / 96) * 96 + idx % 96];
  for (int p = t; p < 544; p += 256) {
    int a = 0, b = 0;
    if (phase == 0) {
      if (p < A1C) { triu_ab(p, 31, a, b); b += 1; }
    } else {
      if (p < P1C) triu_ab(p, 32, a, b);
    }
    pa[p] = (uint8_t)a; pb[p] = (uint8_t)b;
  }
  const int lane = t & 63, wave = t >> 6;
  const int m16 = lane & 15, quad = lane >> 4;
  const int sw8 = (quad ^ ((m16 >> 1) & 3)) * 8;
  const int br = t >> 2;
  const int bc8 = ((t & 3) ^ ((br >> 1) & 3)) * 8;  // swizzled source chunk
  const int lc8 = (t & 3) * 8;                      // LDS column
  const float s2 = 0.70710678118654752f, s6 = 0.40824829046386302f;
  __syncthreads();

  if (phase == 0) {  // ---- o1e: cross pairs ----
    floatx4 acc[3] = {};
    for (int k0 = 0; k0 < 512; k0 += 32) {
      if (k0) __syncthreads();
      {
        half8 g8 = *(const half8*)&G[(n0 + br) * NP2 + (M0C + M1C) + k0 + bc8];
        half8 a0, a1, a2;
#pragma unroll
        for (int j = 0; j < 8; ++j) {
          int p = k0 + bc8 + j;
          if (p < A1C) {
            int a = pa[p], b = pb[p];
            float ax = xv[br][a * 3], ay = xv[br][a * 3 + 1], az = xv[br][a * 3 + 2];
            float bx = xv[br][b * 3], by = xv[br][b * 3 + 1], bz = xv[br][b * 3 + 2];
            float g = (float)g8[j] * s2;
            a0[j] = (_Float16)((ay * bz - az * by) * g);
            a1[j] = (_Float16)((az * bx - ax * bz) * g);
            a2[j] = (_Float16)((ax * by - ay * bx) * g);
          } else {
            a0[j] = (_Float16)0.f; a1[j] = (_Float16)0.f; a2[j] = (_Float16)0.f;
          }
        }
        *(half8*)&As[0][br * 32 + lc8] = a0;
        *(half8*)&As[1][br * 32 + lc8] = a1;
        *(half8*)&As[2][br * 32 + lc8] = a2;
      }
      __syncthreads();
      half8 bf = *(const half8*)&w1eT[(size_t)m16 * 512 + k0 + quad * 8];
#pragma unroll
      for (int i = 0; i < 3; ++i) {
        half8 af = *(const half8*)&As[i][(wave * 16 + m16) * 32 + sw8];
        acc[i] = __builtin_amdgcn_mfma_f32_16x16x32_f16(af, bf, acc[i], 0, 0, 0);
      }
    }
#pragma unroll
    for (int i = 0; i < 3; ++i)
#pragma unroll
      for (int rr = 0; rr < 4; ++rr)
        out[(n0 + wave * 16 + quad * 4 + rr) * 288 + 160 + m16 * 3 + i] = acc[i][rr];
  } else {  // ---- o2: symmetric pairs ----
    floatx4 acc[5] = {};
    for (int k0 = 0; k0 < 544; k0 += 32) {
      if (k0) __syncthreads();
      {
        half8 g8 = *(const half8*)&G[(n0 + br) * NP2 + (M0C + M1C + A1C) + k0 + bc8];
        half8 m0v, m1v, m2v, m3v, m4v;
#pragma unroll
        for (int j = 0; j < 8; ++j) {
          int p = k0 + bc8 + j;
          if (p < P1C) {
            int a = pa[p], b = pb[p];
            float ax = xv[br][a * 3], ay = xv[br][a * 3 + 1], az = xv[br][a * 3 + 2];
            float bx = xv[br][b * 3], by = xv[br][b * 3 + 1], bz = xv[br][b * 3 + 2];
            float c1 = (a == b) ? s2 : 1.f;
            float gw = (float)g8[j] * c1;
            m0v[j] = (_Float16)(s2 * (ax * by + ay * bx) * gw);
            m1v[j] = (_Float16)(s2 * (ay * bz + az * by) * gw);
            m2v[j] = (_Float16)(s2 * (ax * bz + az * bx) * gw);
            m3v[j] = (_Float16)(s2 * (ax * bx - ay * by) * gw);
            m4v[j] = (_Float16)(s6 * (2.f * az * bz - ax * bx - ay * by) * gw);
          } else {
            m0v[j] = (_Float16)0.f; m1v[j] = (_Float16)0.f; m2v[j] = (_Float16)0.f;
            m3v[j] = (_Float16)0.f; m4v[j] = (_Float16)0.f;
          }
        }
        *(half8*)&As[0][br * 32 + lc8] = m0v;
        *(half8*)&As[1][br * 32 + lc8] = m1v;
        *(half8*)&As[2][br * 32 + lc8] = m2v;
        *(half8*)&As[3][br * 32 + lc8] = m3v;
        *(half8*)&As[4][br * 32 + lc8] = m4v;
      }
      __syncthreads();
      half8 bf = *(const half8*)&w2eT[(size_t)m16 * 544 + k0 + quad * 8];
#pragma unroll
      for (int m = 0; m < 5; ++m) {
        half8 af = *(const half8*)&As[m][(wave * 16 + m16) * 32 + sw8];
        acc[m] = __builtin_amdgcn_mfma_f32_16x16x32_f16(af, bf, acc[m], 0, 0, 0);
      }
    }
#pragma unroll
    for (int m = 0; m < 5; ++m)
#pragma unroll
      for (int rr = 0; rr < 4; ++rr)
        out[(n0 + wave * 16 + quad * 4 + rr) * 288 + 208 + m16 * 5 + m] = acc[m][rr];
  }
}

// ---------------------------------------------------------------------------
extern "C" void kernel_launch(void* const* d_in, const int* in_sizes, int n_in,
                              void* d_out, int out_size, void* d_ws, size_t ws_size,
                              hipStream_t stream) {
  const float* xs  = (const float*)d_in[0];
  const float* xv  = (const float*)d_in[1];
  const float* w1  = (const float*)d_in[2];
  const float* w2  = (const float*)d_in[3];
  const float* w0  = (const float*)d_in[4];
  const float* w1o = (const float*)d_in[5];
  const float* w1e = (const float*)d_in[6];
  const float* w2e = (const float*)d_in[7];
  float* out = (float*)d_out;

  char* ws = (char*)d_ws;
  size_t off = 0;
  _Float16* w1T = (_Float16*)(ws + off); off += (size_t)KP * KP * 2;      // 14.45 MB
  _Float16* w2T = (_Float16*)(ws + off); off += (size_t)NP2 * KP * 2;     // 31.65 MB
  _Float16* f0p = (_Float16*)(ws + off); off += (size_t)N_ROWS * KP * 2;  // 44.04 MB
  _Float16* H   = (_Float16*)(ws + off); off += (size_t)N_ROWS * KP * 2;  // 44.04 MB
  _Float16* G   = (_Float16*)(ws + off);                                  // 96.47 MB
  // total ~230.7 MB

  // Small epilogue weights live inside w1T's region (dead after GEMM1).
  _Float16* w0T  = w1T;                                     // 64  x 2688
  _Float16* w1oT = (_Float16*)((char*)w1T + 344064);        // 32  x 2080
  _Float16* w1eT = (_Float16*)((char*)w1T + 477184);        // 32  x 512
  _Float16* w2eT = (_Float16*)((char*)w1T + 509952);        // 32  x 544

  transpose_cvt_kernel<<<dim3(KP / 32, KP / 32), 256, 0, stream>>>(w1, w1T, M0C, M0C, KP);
  transpose_cvt_kernel<<<dim3(KP / 32, NP2 / 32), 256, 0, stream>>>(w2, w2T, M0C, NIR, KP);
  build_f0_kernel<<<N_ROWS, 256, 0, stream>>>(xs, xv, f0p);
  gemm_kernel<true><<<dim3(KP / 128, N_ROWS / 128), 256, 0, stream>>>(f0p, w1T, H, KP, KP, KP, KP);
  // w1T now dead -> overwrite with epilogue weights
  transpose_cvt_kernel<<<dim3(KP / 32, 2), 256, 0, stream>>>(w0, w0T, M0C, 64, KP);
  transpose_cvt_kernel<<<dim3(65, 1), 256, 0, stream>>>(w1o, w1oT, M1C, 32, 2080);
  transpose_cvt_kernel<<<dim3(16, 1), 256, 0, stream>>>(w1e, w1eT, A1C, 16, 512);
  transpose_cvt_kernel<<<dim3(17, 1), 256, 0, stream>>>(w2e, w2eT, P1C, 16, 544);
  gemm_kernel<false><<<dim3(NP2 / 128, N_ROWS / 128), 256, 0, stream>>>(H, w2T, G, KP, KP, KP, NP2);
  epi0_kernel<<<512, 256, 0, stream>>>(f0p, G, w0T, out);
  epi1_kernel<<<256, 256, 0, stream>>>(xs, xv, G, w1oT, out);
  epi1e2_kernel<<<dim3(128, 2), 256, 0, stream>>>(xv, G, w1eT, w2eT, out);
}

// Round 4
// 795.607 us; speedup vs baseline: 2.5013x; 1.1299x over previous
//
#include <hip/hip_runtime.h>
#include <hip/hip_bf16.h>
#include <stdint.h>

// Problem constants
#define N_ROWS 8192
#define M0C 2672    // C0 + P0 + P1 = 64 + 2080 + 528
#define M1C 2080    // C1 + C0*C1
#define A1C 496
#define P1C 528
#define KP  2688    // M0 padded to multiple of 128 (and 64 for BK)
#define NP2 5888    // NUM_IRREPS (5776) padded to multiple of 128
#define NIR 5776
#define M1P 2112    // M1C padded to multiple of 64

typedef __attribute__((ext_vector_type(8))) _Float16 half8;
typedef __attribute__((ext_vector_type(4))) float floatx4;

__device__ __forceinline__ void async_copy16(const _Float16* g, _Float16* l) {
  __builtin_amdgcn_global_load_lds(
      (__attribute__((address_space(1))) void*)(g),
      (__attribute__((address_space(3))) void*)(l), 16, 0, 0);
}

// ---------------------------------------------------------------------------
// Transpose + fp32->fp16 convert with zero padding.
// ---------------------------------------------------------------------------
__global__ __launch_bounds__(256) void transpose_cvt_kernel(
    const float* __restrict__ src, _Float16* __restrict__ dst,
    int srcR, int srcC, int dstC) {
  __shared__ float tile[32][33];
  const int t = threadIdx.x, tx = t & 31, ty = t >> 5;
  const int bx = blockIdx.x, by = blockIdx.y;
#pragma unroll
  for (int i = 0; i < 4; ++i) {
    int sr = bx * 32 + ty + i * 8;   // src row (k dim)
    int sc = by * 32 + tx;           // src col
    tile[ty + i * 8][tx] = (sr < srcR && sc < srcC) ? src[(size_t)sr * srcC + sc] : 0.f;
  }
  __syncthreads();
#pragma unroll
  for (int i = 0; i < 4; ++i) {
    int dr = by * 32 + ty + i * 8;
    int dc = bx * 32 + tx;
    dst[(size_t)dr * dstC + dc] = (_Float16)tile[tx][ty + i * 8];
  }
}

// ---------------------------------------------------------------------------
// triu_indices(C) pair decode: p -> (a, b), b >= a.
// ---------------------------------------------------------------------------
__device__ __forceinline__ void triu_ab(int p, int C, int& a, int& b) {
  float fC = (float)C + 0.5f;
  int ai = (int)(fC - sqrtf(fC * fC - 2.0f * (float)p));
  if (ai < 0) ai = 0;
  while (ai > 0 && ai * C - ai * (ai - 1) / 2 > p) --ai;
  while ((ai + 1) * C - (ai + 1) * ai / 2 <= p) ++ai;
  a = ai;
  b = p - (ai * C - ai * (ai - 1) / 2) + ai;
}

// ---------------------------------------------------------------------------
// f0 = [x_s (64) | ss (2080) | vv0 (528) | zero pad (16)]  as fp16 [N][KP]
// ---------------------------------------------------------------------------
__global__ __launch_bounds__(256) void build_f0_kernel(
    const float* __restrict__ xs_g, const float* __restrict__ xv_g,
    _Float16* __restrict__ f0p) {
  __shared__ float xs[64];
  __shared__ float xv[96];
  const int t = threadIdx.x;
  const size_t n = blockIdx.x;
  if (t < 64) xs[t] = xs_g[n * 64 + t];
  else if (t < 160) xv[t - 64] = xv_g[n * 96 + (t - 64)];
  __syncthreads();
  for (int c = t; c < KP; c += 256) {
    float v;
    if (c < 64) {
      v = xs[c];
    } else if (c < 2144) {                       // ss: pair products of x_s
      int a, b;
      triu_ab(c - 64, 64, a, b);
      v = xs[a] * xs[b] * ((a == b) ? 0.70710678118654752f : 1.f);
    } else if (c < M0C) {                        // vv0: pair dots of x_v
      int a, b;
      triu_ab(c - 2144, 32, a, b);
      float d = xv[a * 3] * xv[b * 3] + xv[a * 3 + 1] * xv[b * 3 + 1] +
                xv[a * 3 + 2] * xv[b * 3 + 2];
      v = d * ((a == b) ? 0.70710678118654752f : 1.f) * 0.57735026918962576f;
    } else {
      v = 0.f;                                   // pad
    }
    f0p[n * KP + c] = (_Float16)v;
  }
}

// ---------------------------------------------------------------------------
// fp16 MFMA GEMM, m97 structure + swizzled LDS + XCD-aware block remap.
// gridDim.y must be 64. XCD i&7 owns row band [xcd*8, xcd*8+8), sweeps cols
// row-fastest: A band (~5.5 MB) stays L2-resident per XCD, B col-tiles reused
// by 8 consecutive row-blocks.
// ---------------------------------------------------------------------------
template <bool SILU>
__global__ __launch_bounds__(256, 3) void gemm_kernel(
    const _Float16* __restrict__ A, const _Float16* __restrict__ B,
    _Float16* __restrict__ C, int K, int lda, int ldb, int ldc) {
  __shared__ alignas(16) _Float16 As[128 * 32];
  __shared__ alignas(16) _Float16 Bs[128 * 32];
  const int tid = threadIdx.x;
  // XCD-aware remap (dispatch order ~ linear id, XCD = id % 8)
  const int gx = gridDim.x;
  const int id = blockIdx.y * gx + blockIdx.x;
  const int jj = id >> 3;
  const int by = (id & 7) * 8 + (jj & 7);
  const int bx = jj >> 3;
  const size_t row0 = (size_t)by * 128;
  const size_t col0 = (size_t)bx * 128;

  const _Float16* ga[2];
  const _Float16* gb[2];
  _Float16* la[2];
  _Float16* lb[2];
#pragma unroll
  for (int i = 0; i < 2; ++i) {
    int c = tid + i * 256;
    int r = c >> 2;
    int scol = (c & 3) ^ ((r >> 1) & 3);   // swizzled source chunk
    ga[i] = A + (row0 + r) * lda + scol * 8;
    gb[i] = B + (col0 + r) * ldb + scol * 8;
    la[i] = &As[c * 8];                    // LDS dest stays lane-contiguous
    lb[i] = &Bs[c * 8];
  }

  const int lane = tid & 63;
  const int wave = tid >> 6;
  const int wm = (wave & 1) * 64;
  const int wn = (wave >> 1) * 64;
  const int m16 = lane & 15;
  const int quad = lane >> 4;
  const int sw8 = (quad ^ ((m16 >> 1) & 3)) * 8;  // swizzled read chunk
  int aoff[4], boff[4];
#pragma unroll
  for (int i = 0; i < 4; ++i) {
    aoff[i] = (wm + i * 16 + m16) * 32 + sw8;
    boff[i] = (wn + i * 16 + m16) * 32 + sw8;
  }

  floatx4 acc[4][4] = {};

  for (int k = 0; k < K; k += 32) {
    if (k) __syncthreads();
#pragma unroll
    for (int i = 0; i < 2; ++i) {
      async_copy16(ga[i] + k, la[i]);
      async_copy16(gb[i] + k, lb[i]);
    }
    __syncthreads();

    half8 af[4], bf[4];
#pragma unroll
    for (int i = 0; i < 4; ++i) af[i] = *(const half8*)&As[aoff[i]];
#pragma unroll
    for (int j = 0; j < 4; ++j) bf[j] = *(const half8*)&Bs[boff[j]];
#pragma unroll
    for (int i = 0; i < 4; ++i)
#pragma unroll
      for (int j = 0; j < 4; ++j)
        acc[i][j] = __builtin_amdgcn_mfma_f32_16x16x32_f16(af[i], bf[j], acc[i][j], 0, 0, 0);
  }

  // C/D layout: col = lane&15, row = quad*4 + reg
#pragma unroll
  for (int i = 0; i < 4; ++i) {
    size_t r = row0 + wm + i * 16 + quad * 4;
#pragma unroll
    for (int j = 0; j < 4; ++j) {
      size_t cc = col0 + wn + j * 16 + m16;
#pragma unroll
      for (int rr = 0; rr < 4; ++rr) {
        float v = acc[i][j][rr];
        if (SILU) v = v / (1.f + __expf(-v));
        C[(r + rr) * ldc + cc] = (_Float16)v;
      }
    }
  }
}

// ---------------------------------------------------------------------------
// epi0: o0 = (f0 .* g0) @ w0.  32 rows/block, BK=64, K=2688, N=64. grid 256.
// All 256 threads build; each wave: 1 row-tile x 2 col-tiles x 2 k-halves.
// LDS XOR swizzle: physical chunk p of row r holds logical chunk p ^ (r&7).
// ---------------------------------------------------------------------------
__global__ __launch_bounds__(256) void epi0_kernel(
    const _Float16* __restrict__ f0p, const _Float16* __restrict__ G,
    const _Float16* __restrict__ w0T, float* __restrict__ out) {
  __shared__ alignas(16) _Float16 As[32 * 64];
  const int t = threadIdx.x;
  const size_t n0 = (size_t)blockIdx.x * 32;
  const int lane = t & 63, wave = t >> 6;
  const int m16 = lane & 15, quad = lane >> 4;
  const int rt = (wave & 1) * 16;        // row tile base
  const int ctb = (wave >> 1) * 32;      // col pair base
  const int br = t >> 3, p = t & 7;      // build: row, physical chunk
  const int l8 = (p ^ (br & 7)) * 8;     // logical k offset

  floatx4 acc[2] = {};
  for (int k0 = 0; k0 < KP; k0 += 64) {
    if (k0) __syncthreads();
    {
      half8 f = *(const half8*)&f0p[(n0 + br) * KP + k0 + l8];
      half8 g = *(const half8*)&G[(n0 + br) * NP2 + k0 + l8];
      half8 a;
#pragma unroll
      for (int j = 0; j < 8; ++j) a[j] = (_Float16)((float)f[j] * (float)g[j]);
      *(half8*)&As[br * 64 + p * 8] = a;
    }
    __syncthreads();
#pragma unroll
    for (int kk = 0; kk < 2; ++kk) {
      int q = kk * 4 + quad;
      half8 af = *(const half8*)&As[(rt + m16) * 64 + (q ^ (m16 & 7)) * 8];
#pragma unroll
      for (int c = 0; c < 2; ++c) {
        half8 bf = *(const half8*)&w0T[(size_t)(ctb + c * 16 + m16) * KP + k0 + kk * 32 + quad * 8];
        acc[c] = __builtin_amdgcn_mfma_f32_16x16x32_f16(af, bf, acc[c], 0, 0, 0);
      }
    }
  }
#pragma unroll
  for (int c = 0; c < 2; ++c)
#pragma unroll
    for (int rr = 0; rr < 4; ++rr)
      out[(n0 + rt + quad * 4 + rr) * 288 + ctb + c * 16 + m16] = acc[c][rr];
}

// ---------------------------------------------------------------------------
// epi1: o1[n][o][i] = sum_c f1[n][c][i]*g1[n][c]*w1o[c][o].
// 32 rows/block, BK=64, K=2080 (padded 2112, w1oT zero-padded), N=32. grid 256.
// ---------------------------------------------------------------------------
__global__ __launch_bounds__(256) void epi1_kernel(
    const float* __restrict__ xs_g, const float* __restrict__ xv_g,
    const _Float16* __restrict__ G, const _Float16* __restrict__ w1oT,
    float* __restrict__ out) {
  __shared__ float xs[32][64];
  __shared__ float xv[32][96];
  __shared__ alignas(16) _Float16 As[3][32 * 64];
  const int t = threadIdx.x;
  const size_t n0 = (size_t)blockIdx.x * 32;
  for (int idx = t; idx < 32 * 64; idx += 256)
    xs[idx >> 6][idx & 63] = xs_g[(n0 + (idx >> 6)) * 64 + (idx & 63)];
  for (int idx = t; idx < 32 * 96; idx += 256)
    xv[idx / 96][idx % 96] = xv_g[(n0 + idx / 96) * 96 + idx % 96];
  const int lane = t & 63, wave = t >> 6;
  const int m16 = lane & 15, quad = lane >> 4;
  const int rt = (wave & 1) * 16;   // row tile
  const int ct = (wave >> 1) * 16;  // col tile
  const int br = t >> 3, p = t & 7;
  const int l8 = (p ^ (br & 7)) * 8;

  floatx4 acc[3] = {};
  __syncthreads();
  for (int k0 = 0; k0 < M1P; k0 += 64) {
    if (k0) __syncthreads();
    {
      half8 g8 = *(const half8*)&G[(n0 + br) * NP2 + M0C + k0 + l8];
      int kbase = k0 + l8;
      half8 a0, a1, a2;
      if (kbase < 32) {
#pragma unroll
        for (int j = 0; j < 8; ++j) {
          float g = (float)g8[j];
          int v = kbase + j;
          a0[j] = (_Float16)(xv[br][v * 3 + 0] * g);
          a1[j] = (_Float16)(xv[br][v * 3 + 1] * g);
          a2[j] = (_Float16)(xv[br][v * 3 + 2] * g);
        }
      } else {
        int s = (kbase - 32) >> 5;
        if (s > 63) s = 63;                  // pad region: B is zero anyway
        int v0 = (kbase - 32) & 31;
        float xsr = xs[br][s];
#pragma unroll
        for (int j = 0; j < 8; ++j) {
          float g = (float)g8[j] * xsr;
          int v = v0 + j;
          a0[j] = (_Float16)(xv[br][v * 3 + 0] * g);
          a1[j] = (_Float16)(xv[br][v * 3 + 1] * g);
          a2[j] = (_Float16)(xv[br][v * 3 + 2] * g);
        }
      }
      *(half8*)&As[0][br * 64 + p * 8] = a0;
      *(half8*)&As[1][br * 64 + p * 8] = a1;
      *(half8*)&As[2][br * 64 + p * 8] = a2;
    }
    __syncthreads();
#pragma unroll
    for (int kk = 0; kk < 2; ++kk) {
      int q = kk * 4 + quad;
      half8 bf = *(const half8*)&w1oT[(size_t)(ct + m16) * M1P + k0 + kk * 32 + quad * 8];
#pragma unroll
      for (int i = 0; i < 3; ++i) {
        half8 af = *(const half8*)&As[i][(rt + m16) * 64 + (q ^ (m16 & 7)) * 8];
        acc[i] = __builtin_amdgcn_mfma_f32_16x16x32_f16(af, bf, acc[i], 0, 0, 0);
      }
    }
  }
#pragma unroll
  for (int i = 0; i < 3; ++i)
#pragma unroll
    for (int rr = 0; rr < 4; ++rr)
      out[(n0 + rt + quad * 4 + rr) * 288 + 64 + (ct + m16) * 3 + i] = acc[i][rr];
}

// ---------------------------------------------------------------------------
// epi1e2: blockIdx.y==0 -> o1e (K=496->512), ==1 -> o2 (K=528->544).
// 64 rows/block, N=16. grid (128, 2).
// ---------------------------------------------------------------------------
__global__ __launch_bounds__(256) void epi1e2_kernel(
    const float* __restrict__ xv_g, const _Float16* __restrict__ G,
    const _Float16* __restrict__ w1eT, const _Float16* __restrict__ w2eT,
    float* __restrict__ out) {
  __shared__ float xv[64][96];
  __shared__ alignas(16) _Float16 As[5][64 * 32];
  __shared__ uint8_t pa[544], pb[544];
  const int t = threadIdx.x;
  const size_t n0 = (size_t)blockIdx.x * 64;
  const int phase = blockIdx.y;
  for (int idx = t; idx < 64 * 96; idx += 256)
    xv[idx / 96][idx % 96] = xv_g[(n0 + idx / 96) * 96 + idx % 96];
  for (int p = t; p < 544; p += 256) {
    int a = 0, b = 0;
    if (phase == 0) {
      if (p < A1C) { triu_ab(p, 31, a, b); b += 1; }
    } else {
      if (p < P1C) triu_ab(p, 32, a, b);
    }
    pa[p] = (uint8_t)a; pb[p] = (uint8_t)b;
  }
  const int lane = t & 63, wave = t >> 6;
  const int m16 = lane & 15, quad = lane >> 4;
  const int sw8 = (quad ^ ((m16 >> 1) & 3)) * 8;
  const int br = t >> 2;
  const int bc8 = ((t & 3) ^ ((br >> 1) & 3)) * 8;  // swizzled source chunk
  const int lc8 = (t & 3) * 8;                      // LDS column
  const float s2 = 0.70710678118654752f, s6 = 0.40824829046386302f;
  __syncthreads();

  if (phase == 0) {  // ---- o1e: cross pairs ----
    floatx4 acc[3] = {};
    for (int k0 = 0; k0 < 512; k0 += 32) {
      if (k0) __syncthreads();
      {
        half8 g8 = *(const half8*)&G[(n0 + br) * NP2 + (M0C + M1C) + k0 + bc8];
        half8 a0, a1, a2;
#pragma unroll
        for (int j = 0; j < 8; ++j) {
          int p = k0 + bc8 + j;
          if (p < A1C) {
            int a = pa[p], b = pb[p];
            float ax = xv[br][a * 3], ay = xv[br][a * 3 + 1], az = xv[br][a * 3 + 2];
            float bx = xv[br][b * 3], by = xv[br][b * 3 + 1], bz = xv[br][b * 3 + 2];
            float g = (float)g8[j] * s2;
            a0[j] = (_Float16)((ay * bz - az * by) * g);
            a1[j] = (_Float16)((az * bx - ax * bz) * g);
            a2[j] = (_Float16)((ax * by - ay * bx) * g);
          } else {
            a0[j] = (_Float16)0.f; a1[j] = (_Float16)0.f; a2[j] = (_Float16)0.f;
          }
        }
        *(half8*)&As[0][br * 32 + lc8] = a0;
        *(half8*)&As[1][br * 32 + lc8] = a1;
        *(half8*)&As[2][br * 32 + lc8] = a2;
      }
      __syncthreads();
      half8 bf = *(const half8*)&w1eT[(size_t)m16 * 512 + k0 + quad * 8];
#pragma unroll
      for (int i = 0; i < 3; ++i) {
        half8 af = *(const half8*)&As[i][(wave * 16 + m16) * 32 + sw8];
        acc[i] = __builtin_amdgcn_mfma_f32_16x16x32_f16(af, bf, acc[i], 0, 0, 0);
      }
    }
#pragma unroll
    for (int i = 0; i < 3; ++i)
#pragma unroll
      for (int rr = 0; rr < 4; ++rr)
        out[(n0 + wave * 16 + quad * 4 + rr) * 288 + 160 + m16 * 3 + i] = acc[i][rr];
  } else {  // ---- o2: symmetric pairs ----
    floatx4 acc[5] = {};
    for (int k0 = 0; k0 < 544; k0 += 32) {
      if (k0) __syncthreads();
      {
        half8 g8 = *(const half8*)&G[(n0 + br) * NP2 + (M0C + M1C + A1C) + k0 + bc8];
        half8 m0v, m1v, m2v, m3v, m4v;
#pragma unroll
        for (int j = 0; j < 8; ++j) {
          int p = k0 + bc8 + j;
          if (p < P1C) {
            int a = pa[p], b = pb[p];
            float ax = xv[br][a * 3], ay = xv[br][a * 3 + 1], az = xv[br][a * 3 + 2];
            float bx = xv[br][b * 3], by = xv[br][b * 3 + 1], bz = xv[br][b * 3 + 2];
            float c1 = (a == b) ? s2 : 1.f;
            float gw = (float)g8[j] * c1;
            m0v[j] = (_Float16)(s2 * (ax * by + ay * bx) * gw);
            m1v[j] = (_Float16)(s2 * (ay * bz + az * by) * gw);
            m2v[j] = (_Float16)(s2 * (ax * bz + az * bx) * gw);
            m3v[j] = (_Float16)(s2 * (ax * bx - ay * by) * gw);
            m4v[j] = (_Float16)(s6 * (2.f * az * bz - ax * bx - ay * by) * gw);
          } else {
            m0v[j] = (_Float16)0.f; m1v[j] = (_Float16)0.f; m2v[j] = (_Float16)0.f;
            m3v[j] = (_Float16)0.f; m4v[j] = (_Float16)0.f;
          }
        }
        *(half8*)&As[0][br * 32 + lc8] = m0v;
        *(half8*)&As[1][br * 32 + lc8] = m1v;
        *(half8*)&As[2][br * 32 + lc8] = m2v;
        *(half8*)&As[3][br * 32 + lc8] = m3v;
        *(half8*)&As[4][br * 32 + lc8] = m4v;
      }
      __syncthreads();
      half8 bf = *(const half8*)&w2eT[(size_t)m16 * 544 + k0 + quad * 8];
#pragma unroll
      for (int m = 0; m < 5; ++m) {
        half8 af = *(const half8*)&As[m][(wave * 16 + m16) * 32 + sw8];
        acc[m] = __builtin_amdgcn_mfma_f32_16x16x32_f16(af, bf, acc[m], 0, 0, 0);
      }
    }
#pragma unroll
    for (int m = 0; m < 5; ++m)
#pragma unroll
      for (int rr = 0; rr < 4; ++rr)
        out[(n0 + wave * 16 + quad * 4 + rr) * 288 + 208 + m16 * 5 + m] = acc[m][rr];
  }
}

// ---------------------------------------------------------------------------
extern "C" void kernel_launch(void* const* d_in, const int* in_sizes, int n_in,
                              void* d_out, int out_size, void* d_ws, size_t ws_size,
                              hipStream_t stream) {
  const float* xs  = (const float*)d_in[0];
  const float* xv  = (const float*)d_in[1];
  const float* w1  = (const float*)d_in[2];
  const float* w2  = (const float*)d_in[3];
  const float* w0  = (const float*)d_in[4];
  const float* w1o = (const float*)d_in[5];
  const float* w1e = (const float*)d_in[6];
  const float* w2e = (const float*)d_in[7];
  float* out = (float*)d_out;

  char* ws = (char*)d_ws;
  size_t off = 0;
  _Float16* w1T = (_Float16*)(ws + off); off += (size_t)KP * KP * 2;      // 14.45 MB
  _Float16* w2T = (_Float16*)(ws + off); off += (size_t)NP2 * KP * 2;     // 31.65 MB
  _Float16* f0p = (_Float16*)(ws + off); off += (size_t)N_ROWS * KP * 2;  // 44.04 MB
  _Float16* H   = (_Float16*)(ws + off); off += (size_t)N_ROWS * KP * 2;  // 44.04 MB
  _Float16* G   = (_Float16*)(ws + off);                                  // 96.47 MB
  // total ~230.7 MB

  // Small epilogue weights live inside w1T's region (dead after GEMM1).
  _Float16* w0T  = w1T;                                     // 64 x 2688 = 344064 B
  _Float16* w1oT = (_Float16*)((char*)w1T + 344064);        // 32 x 2112 = 135168 B
  _Float16* w1eT = (_Float16*)((char*)w1T + 479232);        // 32 x 512  =  32768 B
  _Float16* w2eT = (_Float16*)((char*)w1T + 512000);        // 32 x 544  =  34816 B

  transpose_cvt_kernel<<<dim3(KP / 32, KP / 32), 256, 0, stream>>>(w1, w1T, M0C, M0C, KP);
  transpose_cvt_kernel<<<dim3(KP / 32, NP2 / 32), 256, 0, stream>>>(w2, w2T, M0C, NIR, KP);
  build_f0_kernel<<<N_ROWS, 256, 0, stream>>>(xs, xv, f0p);
  gemm_kernel<true><<<dim3(KP / 128, N_ROWS / 128), 256, 0, stream>>>(f0p, w1T, H, KP, KP, KP, KP);
  // w1T now dead -> overwrite with epilogue weights
  transpose_cvt_kernel<<<dim3(KP / 32, 2), 256, 0, stream>>>(w0, w0T, M0C, 64, KP);
  transpose_cvt_kernel<<<dim3(M1P / 32, 1), 256, 0, stream>>>(w1o, w1oT, M1C, 32, M1P);
  transpose_cvt_kernel<<<dim3(16, 1), 256, 0, stream>>>(w1e, w1eT, A1C, 16, 512);
  transpose_cvt_kernel<<<dim3(17, 1), 256, 0, stream>>>(w2e, w2eT, P1C, 16, 544);
  gemm_kernel<false><<<dim3(NP2 / 128, N_ROWS / 128), 256, 0, stream>>>(H, w2T, G, KP, KP, KP, NP2);
  epi0_kernel<<<256, 256, 0, stream>>>(f0p, G, w0T, out);
  epi1_kernel<<<256, 256, 0, stream>>>(xs, xv, G, w1oT, out);
  epi1e2_kernel<<<dim3(128, 2), 256, 0, stream>>>(xv, G, w1eT, w2eT, out);
}